// Round 1
// baseline (783.650 us; speedup 1.0000x reference)
//
#include <hip/hip_runtime.h>
#include <hip/hip_bf16.h>
#include <cstdint>

#define N_BOX 8192
#define N_WORDS 128   // 8192 / 64

// ---------------- workspace layout ----------------
// sup matrix : 8192*128*8 = 8388608 B   @ 0
// boxes4     : 8192*16    = 131072  B   @ 8388608
// scores     : 8192*4     = 32768   B   @ 8519680
// rank       : 8192*4     = 32768   B   @ 8552448
// mask       : 128*8      = 1024    B   @ 8585216
// maxconf    : 4 B                      @ 8586240
#define OFF_SUP    0
#define OFF_BOXES  8388608
#define OFF_SCORES 8519680
#define OFF_RANK   8552448
#define OFF_MASK   8585216
#define OFF_MAXC   8586240

__device__ __forceinline__ unsigned long long make_key(float s, int idx) {
    // positive floats: bit pattern is order-preserving. Reversed index in the
    // low 13 bits reproduces stable argsort(-conf): equal conf -> lower index first.
    return (((unsigned long long)__float_as_uint(s)) << 13) |
           (unsigned long long)(8191 - idx);
}

// K1: max-reduce conf, zero rank + keep mask
__global__ __launch_bounds__(1024) void k1_max_zero(const float* __restrict__ in,
                                                    float* __restrict__ maxc,
                                                    int* __restrict__ rank,
                                                    unsigned long long* __restrict__ mask) {
    int t = threadIdx.x;
    float m = 0.0f;  // conf is uniform [0,1): non-negative
    for (int k = t; k < N_BOX; k += 1024) m = fmaxf(m, in[k * 5 + 4]);
    for (int off = 32; off; off >>= 1) m = fmaxf(m, __shfl_down(m, off));
    __shared__ float wm[16];
    if ((t & 63) == 0) wm[t >> 6] = m;
    __syncthreads();
    if (t == 0) {
        float mm = wm[0];
        for (int k = 1; k < 16; ++k) mm = fmaxf(mm, wm[k]);
        *maxc = mm;
    }
    for (int k = t; k < N_BOX; k += 1024) rank[k] = 0;
    if (t < N_WORDS) mask[t] = 0ull;
}

// K2: rank[i] = #{ j : key_j > key_i }  (descending sort position, stable ties)
__global__ __launch_bounds__(256) void k2_rank(const float* __restrict__ in,
                                               const float* __restrict__ maxc_p,
                                               int* __restrict__ rank) {
    __shared__ unsigned long long keys[1024];
    int t = threadIdx.x;
    int bx = blockIdx.x;
    int it = bx & 31;       // i tile: 256 boxes
    int jt = bx >> 5;       // j tile: 1024 boxes (8 tiles)
    float maxc = *maxc_p;
    for (int r = 0; r < 4; ++r) {
        int j = jt * 1024 + r * 256 + t;
        float s = __fdiv_rn(in[j * 5 + 4], maxc);
        keys[r * 256 + t] = make_key(s, j);
    }
    __syncthreads();
    int i = it * 256 + t;
    unsigned long long ki = make_key(__fdiv_rn(in[i * 5 + 4], maxc), i);
    int cnt = 0;
    #pragma unroll 8
    for (int k = 0; k < 1024; ++k) cnt += (keys[k] > ki) ? 1 : 0;
    atomicAdd(&rank[i], cnt);
}

// K3: scatter boxes/scores into sorted order, build valid bitmask
__global__ __launch_bounds__(256) void k3_scatter(const float* __restrict__ in,
                                                  const int* __restrict__ rank,
                                                  const float* __restrict__ maxc_p,
                                                  float4* __restrict__ boxes4,
                                                  float* __restrict__ scores,
                                                  unsigned long long* __restrict__ mask) {
    int i = blockIdx.x * 256 + threadIdx.x;
    float cx = in[i * 5 + 0];
    float cy = in[i * 5 + 1];
    float w  = in[i * 5 + 2];
    float h  = in[i * 5 + 3];
    float c  = in[i * 5 + 4];
    float maxc = *maxc_p;
    float s = __fdiv_rn(c, maxc);
    int r = rank[i];
    float4 b;
    b.x = __fsub_rn(cx, __fmul_rn(w, 0.5f));
    b.y = __fsub_rn(cy, __fmul_rn(h, 0.5f));
    b.z = __fadd_rn(cx, __fmul_rn(w, 0.5f));
    b.w = __fadd_rn(cy, __fmul_rn(h, 0.5f));
    boxes4[r] = b;
    scores[r] = s;
    if (s >= 0.5f) atomicOr(&mask[r >> 6], 1ull << (r & 63));
}

// K4: suppression bit matrix. Block covers 64 rows x 256 cols (4 words).
__global__ __launch_bounds__(256) void k4_matrix(const float4* __restrict__ boxes4,
                                                 const float* __restrict__ scores,
                                                 unsigned long long* __restrict__ sup) {
    int i0 = blockIdx.x * 64;      // row tile start
    int wt = blockIdx.y;           // word tile: words wt*4 .. wt*4+3
    if ((wt + 1) * 256 <= i0) return;        // strictly lower triangle: never read
    if (scores[i0] < 0.5f) return;           // whole row tile invalid (scores sorted desc)

    __shared__ float4 bi[64];
    __shared__ float4 bj[256];
    int t = threadIdx.x;
    if (t < 64) bi[t] = boxes4[i0 + t];
    bj[t] = boxes4[wt * 256 + t];
    __syncthreads();

    int il = t >> 2;               // 0..63 local row
    int wl = t & 3;                // 0..3 local word
    int i = i0 + il;
    float4 a = bi[il];
    float aarea = __fmul_rn(__fsub_rn(a.z, a.x), __fsub_rn(a.w, a.y));
    int jbase = wt * 256 + wl * 64;
    unsigned long long word = 0ull;
    #pragma unroll 4
    for (int k = 0; k < 64; ++k) {
        float4 b = bj[wl * 64 + k];
        float ix1 = fmaxf(a.x, b.x);
        float iy1 = fmaxf(a.y, b.y);
        float ix2 = fminf(a.z, b.z);
        float iy2 = fminf(a.w, b.w);
        float iw = fmaxf(__fsub_rn(ix2, ix1), 0.0f);
        float ih = fmaxf(__fsub_rn(iy2, iy1), 0.0f);
        float inter = __fmul_rn(iw, ih);
        float barea = __fmul_rn(__fsub_rn(b.z, b.x), __fsub_rn(b.w, b.y));
        float uni = __fsub_rn(__fadd_rn(aarea, barea), inter);
        float iou = __fdiv_rn(inter, fmaxf(uni, 1e-9f));
        int j = jbase + k;
        if ((iou > 0.5f) && (j > i)) word |= (1ull << k);
    }
    sup[(size_t)i * N_WORDS + wt * 4 + wl] = word;
}

// K5: serial greedy scan — one wave holds the 8192-bit keep mask in registers.
__global__ __launch_bounds__(64) void k5_scan(const unsigned long long* __restrict__ sup,
                                              unsigned long long* __restrict__ mask) {
    int l = threadIdx.x;  // 0..63
    unsigned long long lo = mask[l];        // word l
    unsigned long long hi = mask[64 + l];   // word 64+l
    for (int w = 0; w < N_WORDS; ++w) {
        int owner = w & 63;
        unsigned long long word = __shfl((w < 64) ? lo : hi, owner);
        while (word) {
            int b = __builtin_ctzll(word);
            int i = (w << 6) + b;           // box i is KEPT (bit survived all prior rows)
            const unsigned long long* row = sup + (size_t)i * N_WORDS;
            // only words W >= i>>6 were guaranteed-written (j>i bits); lower words
            // carry no suppression info for row i anyway.
            int wmin = i >> 6;
            if (l >= wmin)      lo &= ~row[l];
            if (64 + l >= wmin) hi &= ~row[64 + l];
            unsigned long long cur = __shfl((w < 64) ? lo : hi, owner);
            word = (b == 63) ? 0ull : (cur & (~0ull << (b + 1)));
        }
    }
    mask[l] = lo;
    mask[64 + l] = hi;
}

// K6: write output rows, zeroed where suppressed
__global__ __launch_bounds__(256) void k6_out(const float4* __restrict__ boxes4,
                                              const float* __restrict__ scores,
                                              const unsigned long long* __restrict__ mask,
                                              float* __restrict__ out) {
    int i = blockIdx.x * 256 + threadIdx.x;
    bool kept = (mask[i >> 6] >> (i & 63)) & 1ull;
    float4 b = boxes4[i];
    float s = scores[i];
    out[i * 5 + 0] = kept ? b.x : 0.0f;
    out[i * 5 + 1] = kept ? b.y : 0.0f;
    out[i * 5 + 2] = kept ? b.z : 0.0f;
    out[i * 5 + 3] = kept ? b.w : 0.0f;
    out[i * 5 + 4] = kept ? s   : 0.0f;
}

extern "C" void kernel_launch(void* const* d_in, const int* in_sizes, int n_in,
                              void* d_out, int out_size, void* d_ws, size_t ws_size,
                              hipStream_t stream) {
    const float* in = (const float*)d_in[0];
    char* ws = (char*)d_ws;
    unsigned long long* sup  = (unsigned long long*)(ws + OFF_SUP);
    float4* boxes4           = (float4*)(ws + OFF_BOXES);
    float* scores            = (float*)(ws + OFF_SCORES);
    int* rank                = (int*)(ws + OFF_RANK);
    unsigned long long* mask = (unsigned long long*)(ws + OFF_MASK);
    float* maxc              = (float*)(ws + OFF_MAXC);
    float* out               = (float*)d_out;

    k1_max_zero<<<1, 1024, 0, stream>>>(in, maxc, rank, mask);
    k2_rank<<<256, 256, 0, stream>>>(in, maxc, rank);
    k3_scatter<<<32, 256, 0, stream>>>(in, rank, maxc, boxes4, scores, mask);
    k4_matrix<<<dim3(128, 32), 256, 0, stream>>>(boxes4, scores, sup);
    k5_scan<<<1, 64, 0, stream>>>(sup, mask);
    k6_out<<<32, 256, 0, stream>>>(boxes4, scores, mask, out);
}